// Round 2
// baseline (5557.187 us; speedup 1.0000x reference)
//
#include <hip/hip_runtime.h>
#include <math.h>

#define BATCH 128
#define SEQN  512
#define XF    128
#define HF    256
#define BC    16    // batch tile per block (per group)
#define HC    8     // h tile per block
#define TCH   8     // time-chunk for phase A
#define NBLK  256
#define NTHR  256
#define NGRP  8     // batch groups
#define GSZ   32    // blocks per group (h tiles)

// ---- LDS layout (word offsets), total 29024 words = 116096 B ----
#define OFF_WX   0        // W_x  [k=128][j=8][g=6]           (6144, persistent)
#define OFF_G    6144     // gates [t=8][g=6][b*8+j]          (6144)
#define OFF_X    12288    // union: A: x [k=128][bt swz]      (16384)
                          //        B: h [k=256][b swz]       (4096)
#define OFF_CM   28672    // cm [b*8+j]                        (128)
#define OFF_TV   28800    // t-values [b*8+t]                  (128)
#define OFF_COEF 28928    // 12 coef vectors x 8               (96)
#define LDS_WORDS 29024
#define LDS_BYTES (LDS_WORDS * 4)

struct Params {
  const float* x;
  const float* t;
  const float* w_h[4];   // fg, ig, in, og   [H][H]
  const float* w_x[6];   // fg, ig, in, og, tg1, tg2  [H][X]
  const float* coef[12]; // fg_b, ig_b, in_b, og_b, og_w_t, tg1_w_t, tg1_b, tg2_w_t, tg2_b, fg_w_c, ig_w_c, og_w_cn
  float* h_buf;          // ws: [2][H][B]  (transposed; all access agent-scope)
  unsigned* ctr;         // ws: [NGRP][4] arrival counters, cacheline-padded
  float* out;
};

__device__ __forceinline__ float sigmoidf_(float v) { return 1.0f / (1.0f + __expf(-v)); }

// in-wave lane exchange over kh = lane&7 (BitMode ds_swizzle: xor<<10 | and 0x1F)
__device__ __forceinline__ float swzx1(float v) { return __int_as_float(__builtin_amdgcn_ds_swizzle(__float_as_int(v), 0x041F)); }
__device__ __forceinline__ float swzx2(float v) { return __int_as_float(__builtin_amdgcn_ds_swizzle(__float_as_int(v), 0x081F)); }
__device__ __forceinline__ float swzx4(float v) { return __int_as_float(__builtin_amdgcn_ds_swizzle(__float_as_int(v), 0x101F)); }

// ---- fence-free sync via per-(group,wave-slot) monotone counters ----------
// Release: explicit s_waitcnt vmcnt(0) drains this wave's agent-scope h
// stores to the coherence point (IF$) before lane0's agent atomicAdd.
// Acquire: every wave polls all 4 slot counters; ctr >= 32*step implies every
// wave of every group member (incl. our own block's) finished step-1:
// its LDS reads are done (restaging OFF_X is safe) and its h stores landed.
__device__ __forceinline__ void post_wave(unsigned* ctr, int gi) {
  asm volatile("s_waitcnt vmcnt(0)" ::: "memory");
  if ((threadIdx.x & 63) == 0) {
    const int wv = threadIdx.x >> 6;
    __hip_atomic_fetch_add(&ctr[(gi * 4 + wv) * 16], 1u,
                           __ATOMIC_RELAXED, __HIP_MEMORY_SCOPE_AGENT);
  }
}

__device__ __forceinline__ void wait_group(const unsigned* ctr, int gi, unsigned target) {
  const int lane = threadIdx.x & 63;
  const bool need = lane < 4;
  const unsigned* f = &ctr[(gi * 4 + (lane & 3)) * 16];
  while (true) {
    unsigned v = need ? __hip_atomic_load(f, __ATOMIC_RELAXED, __HIP_MEMORY_SCOPE_AGENT)
                      : 0u;
    if (__all((int)(!need || v >= target))) break;
  }
}

__global__ __launch_bounds__(NTHR, 1) void timelstm_kernel(Params p) {
  extern __shared__ float sm[];
  const int tid = threadIdx.x;
  const int bid = blockIdx.x;
  const int gi = bid & 7;          // batch group (XCD-resident under round-robin)
  const int mi = bid >> 3;         // member = h tile
  const int b0 = gi * BC;
  const int h0 = mi * HC;

  const int lane = tid & 63;
  const int bq = tid >> 6;         // wave id = batch quad
  const int kh = lane & 7;         // split-K slice (in-wave reducible)
  const int j  = lane >> 3;        // h feature within tile

  // ---- one-time: W_h -> REGISTERS (per-thread slice, reused all 512 steps)
  float wrs[4][32];
#pragma unroll
  for (int g = 0; g < 4; ++g)
#pragma unroll
    for (int q = 0; q < 8; ++q) {
      const float4 v = *(const float4*)&p.w_h[g][(size_t)(h0 + j) * HF + kh * 32 + q * 4];
      wrs[g][q * 4 + 0] = v.x; wrs[g][q * 4 + 1] = v.y;
      wrs[g][q * 4 + 2] = v.z; wrs[g][q * 4 + 3] = v.w;
    }
  // ---- one-time: W_x slab -> LDS ----
  for (int i = tid; i < 6 * 8 * 128; i += NTHR) {     // W_x: [k][j][g]
    int g = i >> 10, jj = (i >> 7) & 7, k = i & 127;
    sm[OFF_WX + k * 48 + jj * 6 + g] = p.w_x[g][(h0 + jj) * XF + k];
  }
  if (tid < 96) sm[OFF_COEF + tid] = p.coef[tid >> 3][h0 + (tid & 7)];
  if (tid < 128) sm[OFF_CM + tid] = 0.0f;             // cm[b*8+j] = 0
  // zero h_buf[0]: member 0 of each group covers its batch columns (agent scope)
  if (mi == 0) {
    unsigned long long* hbu = (unsigned long long*)p.h_buf;
    for (int i = tid; i < HF * BC / 2; i += NTHR) {
      const int k = i >> 3;
      __hip_atomic_store(&hbu[k * (BATCH / 2) + b0 / 2 + (i & 7)], 0ull,
                         __ATOMIC_RELAXED, __HIP_MEMORY_SCOPE_AGENT);
    }
  }
  post_wave(p.ctr, gi);            // init arrival (drains the zero-stores)
  unsigned tstep = 1;
  int cur = 0;

  for (int tc0 = 0; tc0 < SEQN; tc0 += TCH) {
    __syncthreads();   // all waves of this block done with prev chunk's steps
    // ================= phase A: input projections for 8 steps ==========
    // x -> LDS [k=128][bt=128], bt swizzled by ((k>>2)&7)<<2
    {
#pragma unroll
      for (int half = 0; half < 2; ++half) {
        float4 xr[8];
#pragma unroll
        for (int it = 0; it < 8; ++it) {
          const int ri = (half * 8 + it) * 8 + (tid >> 5);   // row = b*8+t
          xr[it] = *(const float4*)&p.x[((size_t)(b0 + (ri >> 3)) * SEQN + (tc0 + (ri & 7))) * XF + (tid & 31) * 4];
        }
#pragma unroll
        for (int it = 0; it < 8; ++it) {
          const int ri = (half * 8 + it) * 8 + (tid >> 5);
          const int k0 = (tid & 31) * 4;
          const float xb[4] = {xr[it].x, xr[it].y, xr[it].z, xr[it].w};
#pragma unroll
          for (int u = 0; u < 4; ++u) {
            const int k = k0 + u;
            sm[OFF_X + k * 128 + (ri ^ (((k >> 2) & 7) << 2))] = xb[u];
          }
        }
      }
      if (tid < 128)   // TV[b*8+t]
        sm[OFF_TV + tid] = p.t[(size_t)(b0 + (tid >> 3)) * SEQN + tc0 + (tid & 7)];
    }
    __syncthreads();
    {
      // thread (c = col-tile of 4 bt, r = j): 6 gates x 4 cols, k = 0..127
      const int c = tid >> 3, r = tid & 7;
      const int c4 = c << 2;
      float a0[4], a1[4], a2[4], a3[4], a4[4], a5[4];
#pragma unroll
      for (int u = 0; u < 4; ++u) { a0[u]=0.f; a1[u]=0.f; a2[u]=0.f; a3[u]=0.f; a4[u]=0.f; a5[u]=0.f; }
      const float* wxp = &sm[OFF_WX + r * 6];
#pragma unroll 4
      for (int k = 0; k < XF; ++k) {
        const float4 xv = *(const float4*)&sm[OFF_X + k * 128 + (c4 ^ (((k >> 2) & 7) << 2))];
        const float2 wA = *(const float2*)&wxp[k * 48 + 0];
        const float2 wB = *(const float2*)&wxp[k * 48 + 2];
        const float2 wC = *(const float2*)&wxp[k * 48 + 4];
        const float xs[4] = {xv.x, xv.y, xv.z, xv.w};
#pragma unroll
        for (int u = 0; u < 4; ++u) {
          a0[u] += wA.x * xs[u]; a1[u] += wA.y * xs[u];
          a2[u] += wB.x * xs[u]; a3[u] += wB.y * xs[u];
          a4[u] += wC.x * xs[u]; a5[u] += wC.y * xs[u];
        }
      }
      const float cfg  = sm[OFF_COEF + 0 * 8 + r], cig  = sm[OFF_COEF + 1 * 8 + r];
      const float cin  = sm[OFF_COEF + 2 * 8 + r];
      const float cogb = sm[OFF_COEF + 3 * 8 + r], cogwt = sm[OFF_COEF + 4 * 8 + r];
      const float ct1w = sm[OFF_COEF + 5 * 8 + r], ct1b = sm[OFF_COEF + 6 * 8 + r];
      const float ct2w = sm[OFF_COEF + 7 * 8 + r], ct2b = sm[OFF_COEF + 8 * 8 + r];
#pragma unroll
      for (int u = 0; u < 4; ++u) {
        const int bt = c4 + u, b = bt >> 3, t = bt & 7;
        const float tv = sm[OFF_TV + bt];
        float* gp = &sm[OFF_G + t * 768 + b * 8 + r];   // [t][g][b*8+j]
        gp[0]   = a0[u] + cfg;
        gp[128] = a1[u] + cig;
        gp[256] = a2[u] + cin;
        gp[384] = a3[u] + cogwt * tv + cogb;
        gp[512] = sigmoidf_(a4[u] + tanhf(ct1w * tv) + ct1b);
        gp[640] = sigmoidf_(a5[u] + tanhf(ct2w * tv) + ct2b);
      }
    }
    __syncthreads();   // phase A done: OFF_X may be restaged with h below

    // ================= phase B: 8 recurrent steps =================
    for (int tt = 0; tt < TCH; ++tt) {
      wait_group(p.ctr, gi, 32u * tstep);
      // stage h tile [k=256][b=16], b swizzled by ((k>>5)&3)<<2
      {
        const unsigned long long* hsrc =
            (const unsigned long long*)(p.h_buf + (size_t)cur * HF * BATCH);
        unsigned long long uv[8];
#pragma unroll
        for (int it = 0; it < 8; ++it) {
          const int i = it * 256 + tid;
          const int k = i >> 3;
          uv[it] = __hip_atomic_load(&hsrc[k * (BATCH / 2) + b0 / 2 + (i & 7)],
                                     __ATOMIC_RELAXED, __HIP_MEMORY_SCOPE_AGENT);
        }
#pragma unroll
        for (int it = 0; it < 8; ++it) {
          const int i = it * 256 + tid;
          const int k = i >> 3, pr = i & 7;
          union { unsigned long long u; float2 f; } cv;
          cv.u = uv[it];
          *(float2*)&sm[OFF_X + k * 16 + ((pr * 2) ^ (((k >> 5) & 3) << 2))] = cv.f;
        }
      }
      __syncthreads();       // the only block barrier per step

      // matmul: thread (bq, j, kh): acc[bi][g] over k = kh*32..+31, W in regs
      float acc[4][4];
#pragma unroll
      for (int bi = 0; bi < 4; ++bi)
#pragma unroll
        for (int g = 0; g < 4; ++g) acc[bi][g] = 0.f;

      const float* hp = &sm[OFF_X + kh * 512 + ((bq ^ (kh & 3)) << 2)];
#pragma unroll
      for (int kk = 0; kk < 32; ++kk) {
        const float4 hv = *(const float4*)&hp[kk * 16];   // h[k][bq*4..+3]
        const float w0 = wrs[0][kk], w1 = wrs[1][kk], w2 = wrs[2][kk], w3 = wrs[3][kk];
        acc[0][0] += hv.x * w0; acc[0][1] += hv.x * w1; acc[0][2] += hv.x * w2; acc[0][3] += hv.x * w3;
        acc[1][0] += hv.y * w0; acc[1][1] += hv.y * w1; acc[1][2] += hv.y * w2; acc[1][3] += hv.y * w3;
        acc[2][0] += hv.z * w0; acc[2][1] += hv.z * w1; acc[2][2] += hv.z * w2; acc[2][3] += hv.z * w3;
        acc[3][0] += hv.w * w0; acc[3][1] += hv.w * w1; acc[3][2] += hv.w * w2; acc[3][3] += hv.w * w3;
      }

      // in-wave reduce-scatter over kh (3 rounds): lane ends with
      // pre[g] = full dot for b = bq*4 + (kh&3)   (kh>=4 duplicates kh-4)
      const int kb0 = kh & 1, kb1 = (kh >> 1) & 1;
      float s1[2][4];
#pragma unroll
      for (int pp = 0; pp < 2; ++pp)
#pragma unroll
        for (int g = 0; g < 4; ++g) {
          const float mine  = kb0 ? acc[2 * pp + 1][g] : acc[2 * pp][g];
          const float yours = kb0 ? acc[2 * pp][g]     : acc[2 * pp + 1][g];
          s1[pp][g] = mine + swzx1(yours);
        }
      float s2[4];
#pragma unroll
      for (int g = 0; g < 4; ++g) {
        const float mine  = kb1 ? s1[1][g] : s1[0][g];
        const float yours = kb1 ? s1[0][g] : s1[1][g];
        s2[g] = mine + swzx2(yours);
      }
      float pre[4];
#pragma unroll
      for (int g = 0; g < 4; ++g) pre[g] = s2[g] + swzx4(s2[g]);

      // gates (all 64 lanes; kh>=4 redundant with kh-4, only kh<4 stores)
      {
        const int bi = kh & 3;
        const int b  = (bq << 2) + bi;
        const int ib = b * 8 + j;
        const float cm = sm[OFF_CM + ib];
        const float* gt = &sm[OFF_G + tt * 768 + ib];
        const float fgx = gt[0],   igx = gt[128], inx = gt[256];
        const float ogx = gt[384], tm1 = gt[512], tm2 = gt[640];
        const float igv = sigmoidf_(sm[OFF_COEF + 10 * 8 + j] * cm + pre[1] + igx);
        const float fgv = sigmoidf_(sm[OFF_COEF + 9 * 8 + j] * cm + pre[0] + fgx);
        const float inn = tanhf(pre[2] + inx);
        const float cbase = fgv * cm, cinn = igv * inn;
        const float cmh = cbase + cinn * tm1;
        const float cmn = cbase + cinn * tm2;
        const float ogv = sigmoidf_(sm[OFF_COEF + 11 * 8 + j] * cmh + pre[3] + ogx);
        const float hn  = ogv * tanhf(cmh);
        const float hn2 = swzx1(hn);                 // partner (b+1) value
        if (kh < 4) {
          sm[OFF_CM + ib] = cmn;
          if (!(kh & 1)) {                           // paired 8B agent-scope h store
            union { float2 f; unsigned long long u; } cv;
            cv.f.x = hn; cv.f.y = hn2;
            unsigned long long* hdst =
                (unsigned long long*)(p.h_buf + (size_t)(cur ^ 1) * HF * BATCH +
                                      (size_t)(h0 + j) * BATCH + b0 + b);
            __hip_atomic_store(hdst, cv.u, __ATOMIC_RELAXED, __HIP_MEMORY_SCOPE_AGENT);
          }
          if (tc0 + tt == SEQN - 1) {
            p.out[(size_t)(b0 + b) * HF + h0 + j] = hn;
            p.out[(size_t)BATCH * HF + (size_t)(b0 + b) * HF + h0 + j] = cmn;
          }
        }
      }
      post_wave(p.ctr, gi);
      ++tstep;
      cur ^= 1;
    }
  }
}

extern "C" void kernel_launch(void* const* d_in, const int* in_sizes, int n_in,
                              void* d_out, int out_size, void* d_ws, size_t ws_size,
                              hipStream_t stream) {
  (void)in_sizes; (void)n_in; (void)out_size; (void)ws_size;
  Params p;
  p.x = (const float*)d_in[0];
  p.t = (const float*)d_in[1];
  p.w_h[0] = (const float*)d_in[3];   // fg_w_h
  p.w_h[1] = (const float*)d_in[7];   // ig_w_h
  p.w_h[2] = (const float*)d_in[10];  // in_w_h
  p.w_h[3] = (const float*)d_in[14];  // og_w_h
  p.w_x[0] = (const float*)d_in[4];   // fg_w_x
  p.w_x[1] = (const float*)d_in[8];   // ig_w_x
  p.w_x[2] = (const float*)d_in[11];  // in_w_x
  p.w_x[3] = (const float*)d_in[15];  // og_w_x
  p.w_x[4] = (const float*)d_in[18];  // tg1_w_x
  p.w_x[5] = (const float*)d_in[21];  // tg2_w_x
  p.coef[0]  = (const float*)d_in[5];   // fg_b
  p.coef[1]  = (const float*)d_in[9];   // ig_b
  p.coef[2]  = (const float*)d_in[12];  // in_b
  p.coef[3]  = (const float*)d_in[16];  // og_b
  p.coef[4]  = (const float*)d_in[17];  // og_w_t
  p.coef[5]  = (const float*)d_in[19];  // tg1_w_t
  p.coef[6]  = (const float*)d_in[20];  // tg1_b
  p.coef[7]  = (const float*)d_in[22];  // tg2_w_t
  p.coef[8]  = (const float*)d_in[23];  // tg2_b
  p.coef[9]  = (const float*)d_in[2];   // fg_w_c
  p.coef[10] = (const float*)d_in[6];   // ig_w_c
  p.coef[11] = (const float*)d_in[13];  // og_w_cn
  p.ctr = (unsigned*)d_ws;                          // [8][4] counters, 64B-padded
  p.h_buf = (float*)((char*)d_ws + 32768);          // [2][H][B] f32 = 256 KiB
  p.out = (float*)d_out;

  hipMemsetAsync(d_ws, 0, 16384, stream);  // counters = 0 each call
  hipFuncSetAttribute((const void*)timelstm_kernel,
                      hipFuncAttributeMaxDynamicSharedMemorySize, LDS_BYTES);
  timelstm_kernel<<<dim3(NBLK), dim3(NTHR), LDS_BYTES, stream>>>(p);
}

// Round 3
// 4316.861 us; speedup vs baseline: 1.2873x; 1.2873x over previous
//
#include <hip/hip_runtime.h>
#include <math.h>

#define BATCH 128
#define SEQN  512
#define XF    128
#define HF    256
#define BC    16    // batch tile per block (per group)
#define HC    8     // h tile per block
#define TCH   8     // time-chunk for phase A
#define NBLK  256
#define NTHR  256
#define NGRP  8     // batch groups
#define GSZ   32    // blocks per group (h tiles)

// ---- LDS layout (word offsets), total 29024 words = 116096 B ----
#define OFF_WX   0        // W_x  [k=128][j=8][g=6]           (6144, persistent)
#define OFF_G    6144     // gates [t=8][g=6][b*8+j]          (6144)
#define OFF_X    12288    // union: A: x [k=128][bt swz]      (16384)
                          //        B: per-wave h [4][1024]   (4096)
#define OFF_CM   28672    // cm [b*8+j]                        (128)
#define OFF_TV   28800    // t-values [b*8+t]                  (128)
#define OFF_COEF 28928    // 12 coef vectors x 8               (96)
#define LDS_WORDS 29024
#define LDS_BYTES (LDS_WORDS * 4)

struct Params {
  const float* x;
  const float* t;
  const float* w_h[4];   // fg, ig, in, og   [H][H]
  const float* w_x[6];   // fg, ig, in, og, tg1, tg2  [H][X]
  const float* coef[12]; // fg_b, ig_b, in_b, og_b, og_w_t, tg1_w_t, tg1_b, tg2_w_t, tg2_b, fg_w_c, ig_w_c, og_w_cn
  float* h_buf;          // ws: [2][H][B]  (transposed; all access agent-scope)
  unsigned* flags;       // ws: [NGRP][GSZ][16]  (64B line per block; 4 wave dwords)
  float* out;
};

__device__ __forceinline__ float sigmoidf_(float v) { return 1.0f / (1.0f + __expf(-v)); }

// in-wave lane exchange over kh = lane&7 (BitMode ds_swizzle: xor<<10 | and 0x1F)
__device__ __forceinline__ float swzx1(float v) { return __int_as_float(__builtin_amdgcn_ds_swizzle(__float_as_int(v), 0x041F)); }
__device__ __forceinline__ float swzx2(float v) { return __int_as_float(__builtin_amdgcn_ds_swizzle(__float_as_int(v), 0x081F)); }
__device__ __forceinline__ float swzx4(float v) { return __int_as_float(__builtin_amdgcn_ds_swizzle(__float_as_int(v), 0x101F)); }

// ---- fence-free sync: per-WAVE monotone store-flags (no RMW anywhere) -----
// Release: explicit s_waitcnt vmcnt(0) drains this wave's agent-scope h
// stores to the coherence point before lane0's relaxed agent flag store.
// Acquire: every wave polls all 128 wave-flags of its group (2 per lane as
// one u64 load). flag >= s implies that wave finished step s-1: its LDS
// reads are done and its h stores landed at the coherence point.
__device__ __forceinline__ void post_wave(unsigned* flags, int gi, int mi, unsigned val) {
  asm volatile("s_waitcnt vmcnt(0)" ::: "memory");
  if ((threadIdx.x & 63) == 0) {
    const int wv = threadIdx.x >> 6;
    __hip_atomic_store(&flags[(gi * GSZ + mi) * 16 + wv], val,
                       __ATOMIC_RELAXED, __HIP_MEMORY_SCOPE_AGENT);
  }
}

__device__ __forceinline__ void wait_group(const unsigned* flags, int gi, unsigned target) {
  const int l = threadIdx.x & 63;
  const unsigned long long* f =
      (const unsigned long long*)&flags[(gi * GSZ + (l >> 1)) * 16 + (l & 1) * 2];
  while (true) {
    const unsigned long long v =
        __hip_atomic_load(f, __ATOMIC_RELAXED, __HIP_MEMORY_SCOPE_AGENT);
    const unsigned lo = (unsigned)v, hi = (unsigned)(v >> 32);
    if (__all((int)(lo >= target && hi >= target))) break;
  }
}

__global__ __launch_bounds__(NTHR, 1) void timelstm_kernel(Params p) {
  extern __shared__ float sm[];
  const int tid = threadIdx.x;
  const int bid = blockIdx.x;
  const int gi = bid & 7;          // batch group (XCD-resident under round-robin)
  const int mi = bid >> 3;         // member = h tile
  const int b0 = gi * BC;
  const int h0 = mi * HC;

  const int lane = tid & 63;
  const int bq = tid >> 6;         // wave id = batch quad
  const int kh = lane & 7;         // split-K slice (in-wave reducible)
  const int j  = lane >> 3;        // h feature within tile

  // ---- one-time: W_h -> REGISTERS (per-thread slice, reused all 512 steps)
  float wrs[4][32];
#pragma unroll
  for (int g = 0; g < 4; ++g)
#pragma unroll
    for (int q = 0; q < 8; ++q) {
      const float4 v = *(const float4*)&p.w_h[g][(size_t)(h0 + j) * HF + kh * 32 + q * 4];
      wrs[g][q * 4 + 0] = v.x; wrs[g][q * 4 + 1] = v.y;
      wrs[g][q * 4 + 2] = v.z; wrs[g][q * 4 + 3] = v.w;
    }
  // ---- one-time: W_x slab -> LDS ----
  for (int i = tid; i < 6 * 8 * 128; i += NTHR) {     // W_x: [k][j][g]
    int g = i >> 10, jj = (i >> 7) & 7, k = i & 127;
    sm[OFF_WX + k * 48 + jj * 6 + g] = p.w_x[g][(h0 + jj) * XF + k];
  }
  if (tid < 96) sm[OFF_COEF + tid] = p.coef[tid >> 3][h0 + (tid & 7)];
  if (tid < 128) sm[OFF_CM + tid] = 0.0f;             // cm[b*8+j] = 0
  // zero h_buf[0]: member 0 of each group covers its batch columns (agent scope)
  if (mi == 0) {
    unsigned long long* hbu = (unsigned long long*)p.h_buf;
    for (int i = tid; i < HF * BC / 2; i += NTHR) {
      const int k = i >> 3;
      __hip_atomic_store(&hbu[k * (BATCH / 2) + b0 / 2 + (i & 7)], 0ull,
                         __ATOMIC_RELAXED, __HIP_MEMORY_SCOPE_AGENT);
    }
  }
  post_wave(p.flags, gi, mi, 1u);  // init arrival (drains the zero-stores)
  unsigned tstep = 1;
  int cur = 0;

  for (int tc0 = 0; tc0 < SEQN; tc0 += TCH) {
    __syncthreads();   // all waves of this block past last chunk's LDS reads
    // ================= phase A: input projections for 8 steps ==========
    // x -> LDS [k=128][bt=128], bt swizzled by ((k>>2)&7)<<2
    {
#pragma unroll
      for (int half = 0; half < 2; ++half) {
        float4 xr[8];
#pragma unroll
        for (int it = 0; it < 8; ++it) {
          const int ri = (half * 8 + it) * 8 + (tid >> 5);   // row = b*8+t
          xr[it] = *(const float4*)&p.x[((size_t)(b0 + (ri >> 3)) * SEQN + (tc0 + (ri & 7))) * XF + (tid & 31) * 4];
        }
#pragma unroll
        for (int it = 0; it < 8; ++it) {
          const int ri = (half * 8 + it) * 8 + (tid >> 5);
          const int k0 = (tid & 31) * 4;
          const float xb[4] = {xr[it].x, xr[it].y, xr[it].z, xr[it].w};
#pragma unroll
          for (int u = 0; u < 4; ++u) {
            const int k = k0 + u;
            sm[OFF_X + k * 128 + (ri ^ (((k >> 2) & 7) << 2))] = xb[u];
          }
        }
      }
      if (tid < 128)   // TV[b*8+t]
        sm[OFF_TV + tid] = p.t[(size_t)(b0 + (tid >> 3)) * SEQN + tc0 + (tid & 7)];
    }
    __syncthreads();
    {
      // thread (c = col-tile of 4 bt, r = j): 6 gates x 4 cols, k = 0..127
      const int c = tid >> 3, r = tid & 7;
      const int c4 = c << 2;
      float a0[4], a1[4], a2[4], a3[4], a4[4], a5[4];
#pragma unroll
      for (int u = 0; u < 4; ++u) { a0[u]=0.f; a1[u]=0.f; a2[u]=0.f; a3[u]=0.f; a4[u]=0.f; a5[u]=0.f; }
      const float* wxp = &sm[OFF_WX + r * 6];
#pragma unroll 4
      for (int k = 0; k < XF; ++k) {
        const float4 xv = *(const float4*)&sm[OFF_X + k * 128 + (c4 ^ (((k >> 2) & 7) << 2))];
        const float2 wA = *(const float2*)&wxp[k * 48 + 0];
        const float2 wB = *(const float2*)&wxp[k * 48 + 2];
        const float2 wC = *(const float2*)&wxp[k * 48 + 4];
        const float xs[4] = {xv.x, xv.y, xv.z, xv.w};
#pragma unroll
        for (int u = 0; u < 4; ++u) {
          a0[u] += wA.x * xs[u]; a1[u] += wA.y * xs[u];
          a2[u] += wB.x * xs[u]; a3[u] += wB.y * xs[u];
          a4[u] += wC.x * xs[u]; a5[u] += wC.y * xs[u];
        }
      }
      const float cfg  = sm[OFF_COEF + 0 * 8 + r], cig  = sm[OFF_COEF + 1 * 8 + r];
      const float cin  = sm[OFF_COEF + 2 * 8 + r];
      const float cogb = sm[OFF_COEF + 3 * 8 + r], cogwt = sm[OFF_COEF + 4 * 8 + r];
      const float ct1w = sm[OFF_COEF + 5 * 8 + r], ct1b = sm[OFF_COEF + 6 * 8 + r];
      const float ct2w = sm[OFF_COEF + 7 * 8 + r], ct2b = sm[OFF_COEF + 8 * 8 + r];
#pragma unroll
      for (int u = 0; u < 4; ++u) {
        const int bt = c4 + u, b = bt >> 3, t = bt & 7;
        const float tv = sm[OFF_TV + bt];
        float* gp = &sm[OFF_G + t * 768 + b * 8 + r];   // [t][g][b*8+j]
        gp[0]   = a0[u] + cfg;
        gp[128] = a1[u] + cig;
        gp[256] = a2[u] + cin;
        gp[384] = a3[u] + cogwt * tv + cogb;
        gp[512] = sigmoidf_(a4[u] + tanhf(ct1w * tv) + ct1b);
        gp[640] = sigmoidf_(a5[u] + tanhf(ct2w * tv) + ct2b);
      }
    }
    __syncthreads();   // phase A done: OFF_X becomes per-wave h space below

    // ================= phase B: 8 recurrent steps, ZERO block barriers ====
    for (int tt = 0; tt < TCH; ++tt) {
      wait_group(p.flags, gi, tstep);
      // wave-private h stage: lane u-loop covers k = u*64+lane, cols bq*4..+3.
      // LDS addr = bq*1024 + (k*4 ^ ((k>>5)&7)<<2): write bank-balanced,
      // read (below) conflict-free with 8-way j-broadcast. No barrier: the
      // region is wave-private; lgkmcnt orders ds_write -> ds_read.
      {
        const float* hsrc = p.h_buf + (size_t)cur * HF * BATCH + b0 + (bq << 2);
        unsigned long long ulo[4], uhi[4];
#pragma unroll
        for (int u = 0; u < 4; ++u) {
          const int k = u * 64 + lane;
          const unsigned long long* src = (const unsigned long long*)(hsrc + (size_t)k * BATCH);
          ulo[u] = __hip_atomic_load(src,     __ATOMIC_RELAXED, __HIP_MEMORY_SCOPE_AGENT);
          uhi[u] = __hip_atomic_load(src + 1, __ATOMIC_RELAXED, __HIP_MEMORY_SCOPE_AGENT);
        }
#pragma unroll
        for (int u = 0; u < 4; ++u) {
          const int k = u * 64 + lane;
          const int addr = OFF_X + (bq << 10) + ((k * 4) ^ (((k >> 5) & 7) << 2));
          union { unsigned long long u64[2]; float4 f; } cv;
          cv.u64[0] = ulo[u]; cv.u64[1] = uhi[u];
          *(float4*)&sm[addr] = cv.f;
        }
      }

      // matmul: thread (bq, j, kh): acc[bi][g] over k = kh*32..+31, W in regs
      float acc[4][4];
#pragma unroll
      for (int bi = 0; bi < 4; ++bi)
#pragma unroll
        for (int g = 0; g < 4; ++g) acc[bi][g] = 0.f;

      const int hbase = OFF_X + (bq << 10) + (kh << 7);   // + kh*128
      const int khx = kh << 2;
#pragma unroll
      for (int kk = 0; kk < 32; ++kk) {
        const int off = ((((kk & 7) << 2) ^ khx)) + ((kk >> 3) << 5);
        const float4 hv = *(const float4*)&sm[hbase + off];   // h[k][bq*4..+3]
        const float w0 = wrs[0][kk], w1 = wrs[1][kk], w2 = wrs[2][kk], w3 = wrs[3][kk];
        acc[0][0] += hv.x * w0; acc[0][1] += hv.x * w1; acc[0][2] += hv.x * w2; acc[0][3] += hv.x * w3;
        acc[1][0] += hv.y * w0; acc[1][1] += hv.y * w1; acc[1][2] += hv.y * w2; acc[1][3] += hv.y * w3;
        acc[2][0] += hv.z * w0; acc[2][1] += hv.z * w1; acc[2][2] += hv.z * w2; acc[2][3] += hv.z * w3;
        acc[3][0] += hv.w * w0; acc[3][1] += hv.w * w1; acc[3][2] += hv.w * w2; acc[3][3] += hv.w * w3;
      }

      // in-wave reduce-scatter over kh (3 rounds): lane ends with
      // pre[g] = full dot for b = bq*4 + (kh&3)   (kh>=4 duplicates kh-4)
      const int kb0 = kh & 1, kb1 = (kh >> 1) & 1;
      float s1[2][4];
#pragma unroll
      for (int pp = 0; pp < 2; ++pp)
#pragma unroll
        for (int g = 0; g < 4; ++g) {
          const float mine  = kb0 ? acc[2 * pp + 1][g] : acc[2 * pp][g];
          const float yours = kb0 ? acc[2 * pp][g]     : acc[2 * pp + 1][g];
          s1[pp][g] = mine + swzx1(yours);
        }
      float s2[4];
#pragma unroll
      for (int g = 0; g < 4; ++g) {
        const float mine  = kb1 ? s1[1][g] : s1[0][g];
        const float yours = kb1 ? s1[0][g] : s1[1][g];
        s2[g] = mine + swzx2(yours);
      }
      float pre[4];
#pragma unroll
      for (int g = 0; g < 4; ++g) pre[g] = s2[g] + swzx4(s2[g]);

      // gates (all 64 lanes; kh>=4 redundant with kh-4, only kh<4 stores)
      {
        const int bi = kh & 3;
        const int b  = (bq << 2) + bi;
        const int ib = b * 8 + j;
        const float cm = sm[OFF_CM + ib];
        const float* gt = &sm[OFF_G + tt * 768 + ib];
        const float fgx = gt[0],   igx = gt[128], inx = gt[256];
        const float ogx = gt[384], tm1 = gt[512], tm2 = gt[640];
        const float igv = sigmoidf_(sm[OFF_COEF + 10 * 8 + j] * cm + pre[1] + igx);
        const float fgv = sigmoidf_(sm[OFF_COEF + 9 * 8 + j] * cm + pre[0] + fgx);
        const float inn = tanhf(pre[2] + inx);
        const float cbase = fgv * cm, cinn = igv * inn;
        const float cmh = cbase + cinn * tm1;
        const float cmn = cbase + cinn * tm2;
        const float ogv = sigmoidf_(sm[OFF_COEF + 11 * 8 + j] * cmh + pre[3] + ogx);
        const float hn  = ogv * tanhf(cmh);
        const float hn2 = swzx1(hn);                 // partner (b+1) value
        if (kh < 4) {
          sm[OFF_CM + ib] = cmn;
          if (!(kh & 1)) {                           // paired 8B agent-scope h store
            union { float2 f; unsigned long long u; } cv;
            cv.f.x = hn; cv.f.y = hn2;
            unsigned long long* hdst =
                (unsigned long long*)(p.h_buf + (size_t)(cur ^ 1) * HF * BATCH +
                                      (size_t)(h0 + j) * BATCH + b0 + b);
            __hip_atomic_store(hdst, cv.u, __ATOMIC_RELAXED, __HIP_MEMORY_SCOPE_AGENT);
          }
          if (tc0 + tt == SEQN - 1) {
            p.out[(size_t)(b0 + b) * HF + h0 + j] = hn;
            p.out[(size_t)BATCH * HF + (size_t)(b0 + b) * HF + h0 + j] = cmn;
          }
        }
      }
      post_wave(p.flags, gi, mi, tstep + 1);
      ++tstep;
      cur ^= 1;
    }
  }
}

extern "C" void kernel_launch(void* const* d_in, const int* in_sizes, int n_in,
                              void* d_out, int out_size, void* d_ws, size_t ws_size,
                              hipStream_t stream) {
  (void)in_sizes; (void)n_in; (void)out_size; (void)ws_size;
  Params p;
  p.x = (const float*)d_in[0];
  p.t = (const float*)d_in[1];
  p.w_h[0] = (const float*)d_in[3];   // fg_w_h
  p.w_h[1] = (const float*)d_in[7];   // ig_w_h
  p.w_h[2] = (const float*)d_in[10];  // in_w_h
  p.w_h[3] = (const float*)d_in[14];  // og_w_h
  p.w_x[0] = (const float*)d_in[4];   // fg_w_x
  p.w_x[1] = (const float*)d_in[8];   // ig_w_x
  p.w_x[2] = (const float*)d_in[11];  // in_w_x
  p.w_x[3] = (const float*)d_in[15];  // og_w_x
  p.w_x[4] = (const float*)d_in[18];  // tg1_w_x
  p.w_x[5] = (const float*)d_in[21];  // tg2_w_x
  p.coef[0]  = (const float*)d_in[5];   // fg_b
  p.coef[1]  = (const float*)d_in[9];   // ig_b
  p.coef[2]  = (const float*)d_in[12];  // in_b
  p.coef[3]  = (const float*)d_in[16];  // og_b
  p.coef[4]  = (const float*)d_in[17];  // og_w_t
  p.coef[5]  = (const float*)d_in[19];  // tg1_w_t
  p.coef[6]  = (const float*)d_in[20];  // tg1_b
  p.coef[7]  = (const float*)d_in[22];  // tg2_w_t
  p.coef[8]  = (const float*)d_in[23];  // tg2_b
  p.coef[9]  = (const float*)d_in[2];   // fg_w_c
  p.coef[10] = (const float*)d_in[6];   // ig_w_c
  p.coef[11] = (const float*)d_in[13];  // og_w_cn
  p.flags = (unsigned*)d_ws;                        // [8][32][16] u32 = 16 KiB
  p.h_buf = (float*)((char*)d_ws + 32768);          // [2][H][B] f32 = 256 KiB
  p.out = (float*)d_out;

  hipMemsetAsync(d_ws, 0, 16384, stream);  // wave flags = 0 each call
  hipFuncSetAttribute((const void*)timelstm_kernel,
                      hipFuncAttributeMaxDynamicSharedMemorySize, LDS_BYTES);
  timelstm_kernel<<<dim3(NBLK), dim3(NTHR), LDS_BYTES, stream>>>(p);
}

// Round 4
// 3283.313 us; speedup vs baseline: 1.6926x; 1.3148x over previous
//
#include <hip/hip_runtime.h>
#include <math.h>

#define BATCH 128
#define SEQN  512
#define XF    128
#define HF    256
#define BC    16    // batch tile per block (per group)
#define HC    8     // h tile per block
#define TCH   8     // time-chunk for phase A
#define NBLK  256
#define NTHR  256
#define NGRP  8     // batch groups
#define GSZ   32    // blocks per group (h tiles)

// ---- LDS layout (word offsets), total 29024 words = 116096 B ----
#define OFF_WX   0        // W_x  [k=128][j=8][g=6]           (6144, persistent)
#define OFF_G    6144     // gates [t=8][g=6][b*8+j]          (6144)
#define OFF_X    12288    // union: A: x [k=128][bt swz]      (16384)
                          //        B: per-wave h [4][1024]   (4096)
#define OFF_CM   28672    // cm [b*8+j]                        (128)
#define OFF_TV   28800    // t-values [b*8+t]                  (128)
#define OFF_COEF 28928    // 12 coef vectors x 8               (96)
#define LDS_WORDS 29024
#define LDS_BYTES (LDS_WORDS * 4)

struct Params {
  const float* x;
  const float* t;
  const float* w_h[4];   // fg, ig, in, og   [H][H]
  const float* w_x[6];   // fg, ig, in, og, tg1, tg2  [H][X]
  const float* coef[12]; // fg_b, ig_b, in_b, og_b, og_w_t, tg1_w_t, tg1_b, tg2_w_t, tg2_b, fg_w_c, ig_w_c, og_w_cn
  float* h_buf;          // ws: [2][B][H]  (batch-major: coalesced row reads)
  unsigned* flags;       // ws: [NGRP][GSZ][16]  (64B line per block; 4 wave dwords)
  float* out;
};

__device__ __forceinline__ float sigmoidf_(float v) { return 1.0f / (1.0f + __expf(-v)); }

// in-wave lane exchange (BitMode ds_swizzle: xor<<10 | 0x1F)
__device__ __forceinline__ float swzx1(float v) { return __int_as_float(__builtin_amdgcn_ds_swizzle(__float_as_int(v), 0x041F)); }
__device__ __forceinline__ float swzx2(float v) { return __int_as_float(__builtin_amdgcn_ds_swizzle(__float_as_int(v), 0x081F)); }
__device__ __forceinline__ float swzx4(float v) { return __int_as_float(__builtin_amdgcn_ds_swizzle(__float_as_int(v), 0x101F)); }
__device__ __forceinline__ float swzx8(float v) { return __int_as_float(__builtin_amdgcn_ds_swizzle(__float_as_int(v), 0x201F)); }

// ---- fence-free sync: per-WAVE monotone store-flags (no RMW anywhere) -----
// Release: explicit s_waitcnt vmcnt(0) drains this wave's agent-scope h
// stores to the coherence point before lane0's relaxed agent flag store.
// Acquire: every wave polls all 128 wave-flags of its group (2 per lane as
// one u64 load). flag >= s implies that wave finished step s-1: its LDS
// reads are done and its h stores landed at the coherence point.
__device__ __forceinline__ void post_wave(unsigned* flags, int gi, int mi, unsigned val) {
  asm volatile("s_waitcnt vmcnt(0)" ::: "memory");
  if ((threadIdx.x & 63) == 0) {
    const int wv = threadIdx.x >> 6;
    __hip_atomic_store(&flags[(gi * GSZ + mi) * 16 + wv], val,
                       __ATOMIC_RELAXED, __HIP_MEMORY_SCOPE_AGENT);
  }
}

__device__ __forceinline__ void wait_group(const unsigned* flags, int gi, unsigned target) {
  const int l = threadIdx.x & 63;
  const unsigned long long* f =
      (const unsigned long long*)&flags[(gi * GSZ + (l >> 1)) * 16 + (l & 1) * 2];
  while (true) {
    const unsigned long long v =
        __hip_atomic_load(f, __ATOMIC_RELAXED, __HIP_MEMORY_SCOPE_AGENT);
    const unsigned lo = (unsigned)v, hi = (unsigned)(v >> 32);
    if (__all((int)(lo >= target && hi >= target))) break;
  }
}

__global__ __launch_bounds__(NTHR, 1) void timelstm_kernel(Params p) {
  extern __shared__ float sm[];
  const int tid = threadIdx.x;
  const int bid = blockIdx.x;
  const int gi = bid & 7;          // batch group (XCD-resident under round-robin)
  const int mi = bid >> 3;         // member = h tile
  const int b0 = gi * BC;
  const int h0 = mi * HC;

  const int lane = tid & 63;
  const int bq = tid >> 6;         // wave id = batch quad
  const int kh = lane & 7;         // split-K slice (in-wave reducible)
  const int j  = lane >> 3;        // h feature within tile

  // ---- one-time: W_h -> REGISTERS (per-thread slice, reused all 512 steps)
  float wrs[4][32];
#pragma unroll
  for (int g = 0; g < 4; ++g)
#pragma unroll
    for (int q = 0; q < 8; ++q) {
      const float4 v = *(const float4*)&p.w_h[g][(size_t)(h0 + j) * HF + kh * 32 + q * 4];
      wrs[g][q * 4 + 0] = v.x; wrs[g][q * 4 + 1] = v.y;
      wrs[g][q * 4 + 2] = v.z; wrs[g][q * 4 + 3] = v.w;
    }
  // ---- one-time: W_x slab -> LDS ----
  for (int i = tid; i < 6 * 8 * 128; i += NTHR) {     // W_x: [k][j][g]
    int g = i >> 10, jj = (i >> 7) & 7, k = i & 127;
    sm[OFF_WX + k * 48 + jj * 6 + g] = p.w_x[g][(h0 + jj) * XF + k];
  }
  if (tid < 96) sm[OFF_COEF + tid] = p.coef[tid >> 3][h0 + (tid & 7)];
  if (tid < 128) sm[OFF_CM + tid] = 0.0f;             // cm[b*8+j] = 0
  // zero h_buf[0] rows b0..b0+15: member 0 of each group (contiguous, agent scope)
  if (mi == 0) {
    unsigned long long* hbu = (unsigned long long*)p.h_buf + (size_t)b0 * (HF / 2);
    for (int i = tid; i < BC * HF / 2; i += NTHR) {
      __hip_atomic_store(&hbu[i], 0ull, __ATOMIC_RELAXED, __HIP_MEMORY_SCOPE_AGENT);
    }
  }
  post_wave(p.flags, gi, mi, 1u);  // init arrival (drains the zero-stores)
  unsigned tstep = 1;
  int cur = 0;

  for (int tc0 = 0; tc0 < SEQN; tc0 += TCH) {
    __syncthreads();   // all waves of this block past last chunk's LDS reads
    // ================= phase A: input projections for 8 steps ==========
    // x -> LDS [k=128][bt=128], bt swizzled by ((k>>2)&7)<<2
    {
#pragma unroll
      for (int half = 0; half < 2; ++half) {
        float4 xr[8];
#pragma unroll
        for (int it = 0; it < 8; ++it) {
          const int ri = (half * 8 + it) * 8 + (tid >> 5);   // row = b*8+t
          xr[it] = *(const float4*)&p.x[((size_t)(b0 + (ri >> 3)) * SEQN + (tc0 + (ri & 7))) * XF + (tid & 31) * 4];
        }
#pragma unroll
        for (int it = 0; it < 8; ++it) {
          const int ri = (half * 8 + it) * 8 + (tid >> 5);
          const int k0 = (tid & 31) * 4;
          const float xb[4] = {xr[it].x, xr[it].y, xr[it].z, xr[it].w};
#pragma unroll
          for (int u = 0; u < 4; ++u) {
            const int k = k0 + u;
            sm[OFF_X + k * 128 + (ri ^ (((k >> 2) & 7) << 2))] = xb[u];
          }
        }
      }
      if (tid < 128)   // TV[b*8+t]
        sm[OFF_TV + tid] = p.t[(size_t)(b0 + (tid >> 3)) * SEQN + tc0 + (tid & 7)];
    }
    __syncthreads();
    {
      // thread (c = col-tile of 4 bt, r = j): 6 gates x 4 cols, k = 0..127
      const int c = tid >> 3, r = tid & 7;
      const int c4 = c << 2;
      float a0[4], a1[4], a2[4], a3[4], a4[4], a5[4];
#pragma unroll
      for (int u = 0; u < 4; ++u) { a0[u]=0.f; a1[u]=0.f; a2[u]=0.f; a3[u]=0.f; a4[u]=0.f; a5[u]=0.f; }
      const float* wxp = &sm[OFF_WX + r * 6];
#pragma unroll 4
      for (int k = 0; k < XF; ++k) {
        const float4 xv = *(const float4*)&sm[OFF_X + k * 128 + (c4 ^ (((k >> 2) & 7) << 2))];
        const float2 wA = *(const float2*)&wxp[k * 48 + 0];
        const float2 wB = *(const float2*)&wxp[k * 48 + 2];
        const float2 wC = *(const float2*)&wxp[k * 48 + 4];
        const float xs[4] = {xv.x, xv.y, xv.z, xv.w};
#pragma unroll
        for (int u = 0; u < 4; ++u) {
          a0[u] += wA.x * xs[u]; a1[u] += wA.y * xs[u];
          a2[u] += wB.x * xs[u]; a3[u] += wB.y * xs[u];
          a4[u] += wC.x * xs[u]; a5[u] += wC.y * xs[u];
        }
      }
      const float cfg  = sm[OFF_COEF + 0 * 8 + r], cig  = sm[OFF_COEF + 1 * 8 + r];
      const float cin  = sm[OFF_COEF + 2 * 8 + r];
      const float cogb = sm[OFF_COEF + 3 * 8 + r], cogwt = sm[OFF_COEF + 4 * 8 + r];
      const float ct1w = sm[OFF_COEF + 5 * 8 + r], ct1b = sm[OFF_COEF + 6 * 8 + r];
      const float ct2w = sm[OFF_COEF + 7 * 8 + r], ct2b = sm[OFF_COEF + 8 * 8 + r];
#pragma unroll
      for (int u = 0; u < 4; ++u) {
        const int bt = c4 + u, b = bt >> 3, t = bt & 7;
        const float tv = sm[OFF_TV + bt];
        float* gp = &sm[OFF_G + t * 768 + b * 8 + r];   // [t][g][b*8+j]
        gp[0]   = a0[u] + cfg;
        gp[128] = a1[u] + cig;
        gp[256] = a2[u] + cin;
        gp[384] = a3[u] + cogwt * tv + cogb;
        gp[512] = sigmoidf_(a4[u] + tanhf(ct1w * tv) + ct1b);
        gp[640] = sigmoidf_(a5[u] + tanhf(ct2w * tv) + ct2b);
      }
    }
    __syncthreads();   // phase A done: OFF_X becomes per-wave h space below

    // ================= phase B: 8 recurrent steps, ZERO block barriers ====
    for (int tt = 0; tt < TCH; ++tt) {
      wait_group(p.flags, gi, tstep);
      // wave-private h stage, COALESCED: h_buf is [B][H]; wave bq reads its 4
      // rows (b0+bq*4..+3), each 1KB contiguous (lane l covers cols 4l..4l+3),
      // then transposes into the swizzled wave-private region:
      //   addr(k,bi) = (k*4 ^ ((k>>5)&7)<<2) + bi  -- matmul reads conflict-free.
      // No barrier: region is wave-private; in-order DS pipe handles WAR.
      {
        const unsigned long long* hsrc = (const unsigned long long*)
            (p.h_buf + (size_t)cur * BATCH * HF + (size_t)(b0 + (bq << 2)) * HF);
        unsigned long long v[4][2];
#pragma unroll
        for (int u = 0; u < 4; ++u) {
          const unsigned long long* src = hsrc + (size_t)u * (HF / 2) + lane * 2;
          v[u][0] = __hip_atomic_load(src,     __ATOMIC_RELAXED, __HIP_MEMORY_SCOPE_AGENT);
          v[u][1] = __hip_atomic_load(src + 1, __ATOMIC_RELAXED, __HIP_MEMORY_SCOPE_AGENT);
        }
        float f[4][4];   // [row u][elem e]: h[b=bq*4+u][k=4*lane+e]
#pragma unroll
        for (int u = 0; u < 4; ++u) {
          union { unsigned long long u64; float2 f2; } c0, c1;
          c0.u64 = v[u][0]; c1.u64 = v[u][1];
          f[u][0] = c0.f2.x; f[u][1] = c0.f2.y; f[u][2] = c1.f2.x; f[u][3] = c1.f2.y;
        }
        const int swz = ((lane >> 3) & 7) << 2;
        const int wbase = OFF_X + (bq << 10);
#pragma unroll
        for (int e = 0; e < 4; ++e) {
          const int a = wbase + (((lane << 4) + (e << 2)) ^ swz);
          float2 lo = {f[0][e], f[1][e]};
          float2 hi = {f[2][e], f[3][e]};
          *(float2*)&sm[a]     = lo;   // bi = 0,1
          *(float2*)&sm[a + 2] = hi;   // bi = 2,3
        }
      }

      // matmul: thread (bq, j, kh): acc[bi][g] over k = kh*32..+31, W in regs
      float acc[4][4];
#pragma unroll
      for (int bi = 0; bi < 4; ++bi)
#pragma unroll
        for (int g = 0; g < 4; ++g) acc[bi][g] = 0.f;

      const int hbase = OFF_X + (bq << 10) + (kh << 7);   // + kh*128
      const int khx = kh << 2;
#pragma unroll
      for (int kk = 0; kk < 32; ++kk) {
        const int off = ((((kk & 7) << 2) ^ khx)) + ((kk >> 3) << 5);
        const float4 hv = *(const float4*)&sm[hbase + off];   // h[k][bq*4..+3]
        const float w0 = wrs[0][kk], w1 = wrs[1][kk], w2 = wrs[2][kk], w3 = wrs[3][kk];
        acc[0][0] += hv.x * w0; acc[0][1] += hv.x * w1; acc[0][2] += hv.x * w2; acc[0][3] += hv.x * w3;
        acc[1][0] += hv.y * w0; acc[1][1] += hv.y * w1; acc[1][2] += hv.y * w2; acc[1][3] += hv.y * w3;
        acc[2][0] += hv.z * w0; acc[2][1] += hv.z * w1; acc[2][2] += hv.z * w2; acc[2][3] += hv.z * w3;
        acc[3][0] += hv.w * w0; acc[3][1] += hv.w * w1; acc[3][2] += hv.w * w2; acc[3][3] += hv.w * w3;
      }

      // in-wave reduce-scatter over kh (3 rounds): lane ends with
      // pre[g] = full dot for b = bq*4 + (kh&3)   (kh>=4 duplicates kh-4)
      const int kb0 = kh & 1, kb1 = (kh >> 1) & 1;
      float s1[2][4];
#pragma unroll
      for (int pp = 0; pp < 2; ++pp)
#pragma unroll
        for (int g = 0; g < 4; ++g) {
          const float mine  = kb0 ? acc[2 * pp + 1][g] : acc[2 * pp][g];
          const float yours = kb0 ? acc[2 * pp][g]     : acc[2 * pp + 1][g];
          s1[pp][g] = mine + swzx1(yours);
        }
      float s2[4];
#pragma unroll
      for (int g = 0; g < 4; ++g) {
        const float mine  = kb1 ? s1[1][g] : s1[0][g];
        const float yours = kb1 ? s1[0][g] : s1[1][g];
        s2[g] = mine + swzx2(yours);
      }
      float pre[4];
#pragma unroll
      for (int g = 0; g < 4; ++g) pre[g] = s2[g] + swzx4(s2[g]);

      // gates (all 64 lanes; kh>=4 redundant with kh-4, only kh<4 stores)
      {
        const int bi = kh & 3;
        const int b  = (bq << 2) + bi;
        const int ib = b * 8 + j;
        const float cm = sm[OFF_CM + ib];
        const float* gt = &sm[OFF_G + tt * 768 + ib];
        const float fgx = gt[0],   igx = gt[128], inx = gt[256];
        const float ogx = gt[384], tm1 = gt[512], tm2 = gt[640];
        const float igv = sigmoidf_(sm[OFF_COEF + 10 * 8 + j] * cm + pre[1] + igx);
        const float fgv = sigmoidf_(sm[OFF_COEF + 9 * 8 + j] * cm + pre[0] + fgx);
        const float inn = tanhf(pre[2] + inx);
        const float cbase = fgv * cm, cinn = igv * inn;
        const float cmh = cbase + cinn * tm1;
        const float cmn = cbase + cinn * tm2;
        const float ogv = sigmoidf_(sm[OFF_COEF + 11 * 8 + j] * cmh + pre[3] + ogx);
        const float hn  = ogv * tanhf(cmh);
        const float hn2 = swzx8(hn);                 // partner (j^1) value
        if (kh < 4) {
          sm[OFF_CM + ib] = cmn;
          if (!(j & 1)) {                            // paired 8B store: (j, j+1)
            union { float2 f; unsigned long long u; } cv;
            cv.f.x = hn; cv.f.y = hn2;
            unsigned long long* hdst =
                (unsigned long long*)(p.h_buf + (size_t)(cur ^ 1) * BATCH * HF +
                                      (size_t)(b0 + b) * HF + h0 + j);
            __hip_atomic_store(hdst, cv.u, __ATOMIC_RELAXED, __HIP_MEMORY_SCOPE_AGENT);
          }
          if (tc0 + tt == SEQN - 1) {
            p.out[(size_t)(b0 + b) * HF + h0 + j] = hn;
            p.out[(size_t)BATCH * HF + (size_t)(b0 + b) * HF + h0 + j] = cmn;
          }
        }
      }
      post_wave(p.flags, gi, mi, tstep + 1);
      ++tstep;
      cur ^= 1;
    }
  }
}

extern "C" void kernel_launch(void* const* d_in, const int* in_sizes, int n_in,
                              void* d_out, int out_size, void* d_ws, size_t ws_size,
                              hipStream_t stream) {
  (void)in_sizes; (void)n_in; (void)out_size; (void)ws_size;
  Params p;
  p.x = (const float*)d_in[0];
  p.t = (const float*)d_in[1];
  p.w_h[0] = (const float*)d_in[3];   // fg_w_h
  p.w_h[1] = (const float*)d_in[7];   // ig_w_h
  p.w_h[2] = (const float*)d_in[10];  // in_w_h
  p.w_h[3] = (const float*)d_in[14];  // og_w_h
  p.w_x[0] = (const float*)d_in[4];   // fg_w_x
  p.w_x[1] = (const float*)d_in[8];   // ig_w_x
  p.w_x[2] = (const float*)d_in[11];  // in_w_x
  p.w_x[3] = (const float*)d_in[15];  // og_w_x
  p.w_x[4] = (const float*)d_in[18];  // tg1_w_x
  p.w_x[5] = (const float*)d_in[21];  // tg2_w_x
  p.coef[0]  = (const float*)d_in[5];   // fg_b
  p.coef[1]  = (const float*)d_in[9];   // ig_b
  p.coef[2]  = (const float*)d_in[12];  // in_b
  p.coef[3]  = (const float*)d_in[16];  // og_b
  p.coef[4]  = (const float*)d_in[17];  // og_w_t
  p.coef[5]  = (const float*)d_in[19];  // tg1_w_t
  p.coef[6]  = (const float*)d_in[20];  // tg1_b
  p.coef[7]  = (const float*)d_in[22];  // tg2_w_t
  p.coef[8]  = (const float*)d_in[23];  // tg2_b
  p.coef[9]  = (const float*)d_in[2];   // fg_w_c
  p.coef[10] = (const float*)d_in[6];   // ig_w_c
  p.coef[11] = (const float*)d_in[13];  // og_w_cn
  p.flags = (unsigned*)d_ws;                        // [8][32][16] u32 = 16 KiB
  p.h_buf = (float*)((char*)d_ws + 32768);          // [2][B][H] f32 = 256 KiB
  p.out = (float*)d_out;

  hipMemsetAsync(d_ws, 0, 16384, stream);  // wave flags = 0 each call
  hipFuncSetAttribute((const void*)timelstm_kernel,
                      hipFuncAttributeMaxDynamicSharedMemorySize, LDS_BYTES);
  timelstm_kernel<<<dim3(NBLK), dim3(NTHR), LDS_BYTES, stream>>>(p);
}

// Round 5
// 3017.791 us; speedup vs baseline: 1.8415x; 1.0880x over previous
//
#include <hip/hip_runtime.h>
#include <math.h>

#define BATCH 128
#define SEQN  512
#define XF    128
#define HF    256
#define BC    16    // batch tile per block (per group)
#define HC    8     // h tile per block
#define TCH   8     // time-chunk for phase A
#define NBLK  256
#define NTHR  256
#define NGRP  8     // batch groups
#define GSZ   32    // blocks per group (h tiles)

// ---- LDS layout (word offsets), total 29028 words = 116112 B ----
#define OFF_WX   0        // W_x  [k=128][j=8][g=6]           (6144, persistent)
#define OFF_G    6144     // gates [t=8][g=6][b*8+j]          (6144)
#define OFF_X    12288    // union: A: x [k=128][bt swz]      (16384)
                          //        B: per-wave h [4][1024]   (4096)
#define OFF_CM   28672    // cm [b*8+j]                        (128)
#define OFF_TV   28800    // t-values [b*8+t]                  (128)
#define OFF_COEF 28928    // 12 coef vectors x 8               (96)
#define OFF_GO   29024    // LDS "go" counter for waves 1-3
#define LDS_WORDS 29028
#define LDS_BYTES (LDS_WORDS * 4)

struct Params {
  const float* x;
  const float* t;
  const float* w_h[4];   // fg, ig, in, og   [H][H]
  const float* w_x[6];   // fg, ig, in, og, tg1, tg2  [H][X]
  const float* coef[12]; // fg_b, ig_b, in_b, og_b, og_w_t, tg1_w_t, tg1_b, tg2_w_t, tg2_b, fg_w_c, ig_w_c, og_w_cn
  float* h_buf;          // ws: [2][B][H]  (batch-major: coalesced row reads)
  unsigned* flags;       // ws: [NGRP][GSZ][16]  (64B line per block; 4 wave dwords)
  float* out;
};

__device__ __forceinline__ float sigmoidf_(float v) { return 1.0f / (1.0f + __expf(-v)); }

// in-wave lane exchange (BitMode ds_swizzle: xor<<10 | 0x1F)
__device__ __forceinline__ float swzx1(float v) { return __int_as_float(__builtin_amdgcn_ds_swizzle(__float_as_int(v), 0x041F)); }
__device__ __forceinline__ float swzx2(float v) { return __int_as_float(__builtin_amdgcn_ds_swizzle(__float_as_int(v), 0x081F)); }
__device__ __forceinline__ float swzx4(float v) { return __int_as_float(__builtin_amdgcn_ds_swizzle(__float_as_int(v), 0x101F)); }
__device__ __forceinline__ float swzx8(float v) { return __int_as_float(__builtin_amdgcn_ds_swizzle(__float_as_int(v), 0x201F)); }

// ---- fence-free sync: per-WAVE monotone store-flags, single-poller ---------
// Release: explicit s_waitcnt vmcnt(0) drains this wave's agent-scope h
// stores to the coherence point before lane0's relaxed agent flag store.
// Acquire: ONLY wave 0 polls the 128 wave-flags of the group (64 lanes x u64
// covers 4 dwords of each of 32 block lines), then flips the LDS "go"
// counter; waves 1-3 spin on LDS (no fabric traffic, ~100cy reaction).
// flag >= s implies that wave finished step s-1: its LDS reads are done and
// its h stores landed at the coherence point before its flag became visible.
__device__ __forceinline__ void post_wave(unsigned* flags, int gi, int mi, unsigned val) {
  asm volatile("s_waitcnt vmcnt(0)" ::: "memory");
  if ((threadIdx.x & 63) == 0) {
    const int wv = threadIdx.x >> 6;
    __hip_atomic_store(&flags[(gi * GSZ + mi) * 16 + wv], val,
                       __ATOMIC_RELAXED, __HIP_MEMORY_SCOPE_AGENT);
  }
}

__device__ __forceinline__ void wave_wait(float* sm, const unsigned* flags,
                                          int gi, unsigned target) {
  unsigned* go = (unsigned*)&sm[OFF_GO];
  const int tid = threadIdx.x;
  if (tid < 64) {                      // wave 0: poll all 128 group wave-flags
    const unsigned long long* f =
        (const unsigned long long*)&flags[(gi * GSZ + (tid >> 1)) * 16 + (tid & 1) * 2];
    while (true) {
      const unsigned long long v =
          __hip_atomic_load(f, __ATOMIC_RELAXED, __HIP_MEMORY_SCOPE_AGENT);
      const unsigned lo = (unsigned)v, hi = (unsigned)(v >> 32);
      if (__all((int)(lo >= target && hi >= target))) break;
    }
    if (tid == 0)
      __hip_atomic_store(go, target, __ATOMIC_RELAXED, __HIP_MEMORY_SCOPE_WORKGROUP);
  } else {                             // waves 1-3: LDS spin
    while (__hip_atomic_load(go, __ATOMIC_RELAXED, __HIP_MEMORY_SCOPE_WORKGROUP) < target) {}
  }
  asm volatile("" ::: "memory");       // keep agent h-loads below the spin
}

__global__ __launch_bounds__(NTHR, 1) void timelstm_kernel(Params p) {
  extern __shared__ float sm[];
  const int tid = threadIdx.x;
  const int bid = blockIdx.x;
  const int gi = bid & 7;          // batch group (XCD-resident under round-robin)
  const int mi = bid >> 3;         // member = h tile
  const int b0 = gi * BC;
  const int h0 = mi * HC;

  const int lane = tid & 63;
  const int bq = tid >> 6;         // wave id = batch quad
  const int kh = lane & 7;         // split-K slice (in-wave reducible)
  const int j  = lane >> 3;        // h feature within tile

  // ---- one-time: W_h -> REGISTERS (per-thread slice, reused all 512 steps)
  float wrs[4][32];
#pragma unroll
  for (int g = 0; g < 4; ++g)
#pragma unroll
    for (int q = 0; q < 8; ++q) {
      const float4 v = *(const float4*)&p.w_h[g][(size_t)(h0 + j) * HF + kh * 32 + q * 4];
      wrs[g][q * 4 + 0] = v.x; wrs[g][q * 4 + 1] = v.y;
      wrs[g][q * 4 + 2] = v.z; wrs[g][q * 4 + 3] = v.w;
    }
  // ---- one-time: W_x slab -> LDS ----
  for (int i = tid; i < 6 * 8 * 128; i += NTHR) {     // W_x: [k][j][g]
    int g = i >> 10, jj = (i >> 7) & 7, k = i & 127;
    sm[OFF_WX + k * 48 + jj * 6 + g] = p.w_x[g][(h0 + jj) * XF + k];
  }
  if (tid < 96) sm[OFF_COEF + tid] = p.coef[tid >> 3][h0 + (tid & 7)];
  if (tid < 128) sm[OFF_CM + tid] = 0.0f;             // cm[b*8+j] = 0
  if (tid == 0) *(unsigned*)&sm[OFF_GO] = 0u;
  // zero h_buf[0] rows b0..b0+15: member 0 of each group (contiguous, agent scope)
  if (mi == 0) {
    unsigned long long* hbu = (unsigned long long*)p.h_buf + (size_t)b0 * (HF / 2);
    for (int i = tid; i < BC * HF / 2; i += NTHR) {
      __hip_atomic_store(&hbu[i], 0ull, __ATOMIC_RELAXED, __HIP_MEMORY_SCOPE_AGENT);
    }
  }
  post_wave(p.flags, gi, mi, 1u);  // init arrival (drains the zero-stores)
  unsigned tstep = 1;
  int cur = 0;

  for (int tc0 = 0; tc0 < SEQN; tc0 += TCH) {
    __syncthreads();   // all waves of this block past last chunk's LDS reads
    // ================= phase A: input projections for 8 steps ==========
    // x -> LDS [k=128][bt=128], bt swizzled by ((k>>2)&7)<<2
    {
#pragma unroll
      for (int half = 0; half < 2; ++half) {
        float4 xr[8];
#pragma unroll
        for (int it = 0; it < 8; ++it) {
          const int ri = (half * 8 + it) * 8 + (tid >> 5);   // row = b*8+t
          xr[it] = *(const float4*)&p.x[((size_t)(b0 + (ri >> 3)) * SEQN + (tc0 + (ri & 7))) * XF + (tid & 31) * 4];
        }
#pragma unroll
        for (int it = 0; it < 8; ++it) {
          const int ri = (half * 8 + it) * 8 + (tid >> 5);
          const int k0 = (tid & 31) * 4;
          const float xb[4] = {xr[it].x, xr[it].y, xr[it].z, xr[it].w};
#pragma unroll
          for (int u = 0; u < 4; ++u) {
            const int k = k0 + u;
            sm[OFF_X + k * 128 + (ri ^ (((k >> 2) & 7) << 2))] = xb[u];
          }
        }
      }
      if (tid < 128)   // TV[b*8+t]
        sm[OFF_TV + tid] = p.t[(size_t)(b0 + (tid >> 3)) * SEQN + tc0 + (tid & 7)];
    }
    __syncthreads();
    {
      // thread (c = col-tile of 4 bt, r = j): 6 gates x 4 cols, k = 0..127
      const int c = tid >> 3, r = tid & 7;
      const int c4 = c << 2;
      float a0[4], a1[4], a2[4], a3[4], a4[4], a5[4];
#pragma unroll
      for (int u = 0; u < 4; ++u) { a0[u]=0.f; a1[u]=0.f; a2[u]=0.f; a3[u]=0.f; a4[u]=0.f; a5[u]=0.f; }
      const float* wxp = &sm[OFF_WX + r * 6];
#pragma unroll 4
      for (int k = 0; k < XF; ++k) {
        const float4 xv = *(const float4*)&sm[OFF_X + k * 128 + (c4 ^ (((k >> 2) & 7) << 2))];
        const float2 wA = *(const float2*)&wxp[k * 48 + 0];
        const float2 wB = *(const float2*)&wxp[k * 48 + 2];
        const float2 wC = *(const float2*)&wxp[k * 48 + 4];
        const float xs[4] = {xv.x, xv.y, xv.z, xv.w};
#pragma unroll
        for (int u = 0; u < 4; ++u) {
          a0[u] += wA.x * xs[u]; a1[u] += wA.y * xs[u];
          a2[u] += wB.x * xs[u]; a3[u] += wB.y * xs[u];
          a4[u] += wC.x * xs[u]; a5[u] += wC.y * xs[u];
        }
      }
      const float cfg  = sm[OFF_COEF + 0 * 8 + r], cig  = sm[OFF_COEF + 1 * 8 + r];
      const float cin  = sm[OFF_COEF + 2 * 8 + r];
      const float cogb = sm[OFF_COEF + 3 * 8 + r], cogwt = sm[OFF_COEF + 4 * 8 + r];
      const float ct1w = sm[OFF_COEF + 5 * 8 + r], ct1b = sm[OFF_COEF + 6 * 8 + r];
      const float ct2w = sm[OFF_COEF + 7 * 8 + r], ct2b = sm[OFF_COEF + 8 * 8 + r];
#pragma unroll
      for (int u = 0; u < 4; ++u) {
        const int bt = c4 + u, b = bt >> 3, t = bt & 7;
        const float tv = sm[OFF_TV + bt];
        float* gp = &sm[OFF_G + t * 768 + b * 8 + r];   // [t][g][b*8+j]
        gp[0]   = a0[u] + cfg;
        gp[128] = a1[u] + cig;
        gp[256] = a2[u] + cin;
        gp[384] = a3[u] + cogwt * tv + cogb;
        gp[512] = sigmoidf_(a4[u] + tanhf(ct1w * tv) + ct1b);
        gp[640] = sigmoidf_(a5[u] + tanhf(ct2w * tv) + ct2b);
      }
    }
    __syncthreads();   // phase A done: OFF_X becomes per-wave h space below

    // ================= phase B: 8 recurrent steps, ZERO block barriers ====
    for (int tt = 0; tt < TCH; ++tt) {
      wave_wait(sm, p.flags, gi, tstep);
      // wave-private h stage, COALESCED: h_buf is [B][H]; wave bq reads its 4
      // rows (b0+bq*4..+3), each 1KB contiguous (lane l covers cols 4l..4l+3),
      // then transposes into the swizzled wave-private region:
      //   addr(k,bi) = (k*4 ^ ((k>>5)&7)<<2) + bi  -- matmul reads conflict-free.
      // No barrier: region is wave-private; in-order DS pipe handles WAR.
      {
        const unsigned long long* hsrc = (const unsigned long long*)
            (p.h_buf + (size_t)cur * BATCH * HF + (size_t)(b0 + (bq << 2)) * HF);
        unsigned long long v[4][2];
#pragma unroll
        for (int u = 0; u < 4; ++u) {
          const unsigned long long* src = hsrc + (size_t)u * (HF / 2) + lane * 2;
          v[u][0] = __hip_atomic_load(src,     __ATOMIC_RELAXED, __HIP_MEMORY_SCOPE_AGENT);
          v[u][1] = __hip_atomic_load(src + 1, __ATOMIC_RELAXED, __HIP_MEMORY_SCOPE_AGENT);
        }
        float f[4][4];   // [row u][elem e]: h[b=bq*4+u][k=4*lane+e]
#pragma unroll
        for (int u = 0; u < 4; ++u) {
          union { unsigned long long u64; float2 f2; } c0, c1;
          c0.u64 = v[u][0]; c1.u64 = v[u][1];
          f[u][0] = c0.f2.x; f[u][1] = c0.f2.y; f[u][2] = c1.f2.x; f[u][3] = c1.f2.y;
        }
        const int swz = ((lane >> 3) & 7) << 2;
        const int wbase = OFF_X + (bq << 10);
#pragma unroll
        for (int e = 0; e < 4; ++e) {
          const int a = wbase + (((lane << 4) + (e << 2)) ^ swz);
          float2 lo = {f[0][e], f[1][e]};
          float2 hi = {f[2][e], f[3][e]};
          *(float2*)&sm[a]     = lo;   // bi = 0,1
          *(float2*)&sm[a + 2] = hi;   // bi = 2,3
        }
      }

      // matmul: thread (bq, j, kh): acc[bi][g] over k = kh*32..+31, W in regs
      float acc[4][4];
#pragma unroll
      for (int bi = 0; bi < 4; ++bi)
#pragma unroll
        for (int g = 0; g < 4; ++g) acc[bi][g] = 0.f;

      const int hbase = OFF_X + (bq << 10) + (kh << 7);   // + kh*128
      const int khx = kh << 2;
#pragma unroll
      for (int kk = 0; kk < 32; ++kk) {
        const int off = ((((kk & 7) << 2) ^ khx)) + ((kk >> 3) << 5);
        const float4 hv = *(const float4*)&sm[hbase + off];   // h[k][bq*4..+3]
        const float w0 = wrs[0][kk], w1 = wrs[1][kk], w2 = wrs[2][kk], w3 = wrs[3][kk];
        acc[0][0] += hv.x * w0; acc[0][1] += hv.x * w1; acc[0][2] += hv.x * w2; acc[0][3] += hv.x * w3;
        acc[1][0] += hv.y * w0; acc[1][1] += hv.y * w1; acc[1][2] += hv.y * w2; acc[1][3] += hv.y * w3;
        acc[2][0] += hv.z * w0; acc[2][1] += hv.z * w1; acc[2][2] += hv.z * w2; acc[2][3] += hv.z * w3;
        acc[3][0] += hv.w * w0; acc[3][1] += hv.w * w1; acc[3][2] += hv.w * w2; acc[3][3] += hv.w * w3;
      }

      // in-wave reduce-scatter over kh (3 rounds): lane ends with
      // pre[g] = full dot for b = bq*4 + (kh&3)   (kh>=4 duplicates kh-4)
      const int kb0 = kh & 1, kb1 = (kh >> 1) & 1;
      float s1[2][4];
#pragma unroll
      for (int pp = 0; pp < 2; ++pp)
#pragma unroll
        for (int g = 0; g < 4; ++g) {
          const float mine  = kb0 ? acc[2 * pp + 1][g] : acc[2 * pp][g];
          const float yours = kb0 ? acc[2 * pp][g]     : acc[2 * pp + 1][g];
          s1[pp][g] = mine + swzx1(yours);
        }
      float s2[4];
#pragma unroll
      for (int g = 0; g < 4; ++g) {
        const float mine  = kb1 ? s1[1][g] : s1[0][g];
        const float yours = kb1 ? s1[0][g] : s1[1][g];
        s2[g] = mine + swzx2(yours);
      }
      float pre[4];
#pragma unroll
      for (int g = 0; g < 4; ++g) pre[g] = s2[g] + swzx4(s2[g]);

      // gates (all 64 lanes; kh>=4 redundant with kh-4, only kh<4 stores)
      {
        const int bi = kh & 3;
        const int b  = (bq << 2) + bi;
        const int ib = b * 8 + j;
        const float cm = sm[OFF_CM + ib];
        const float* gt = &sm[OFF_G + tt * 768 + ib];
        const float fgx = gt[0],   igx = gt[128], inx = gt[256];
        const float ogx = gt[384], tm1 = gt[512], tm2 = gt[640];
        const float igv = sigmoidf_(sm[OFF_COEF + 10 * 8 + j] * cm + pre[1] + igx);
        const float fgv = sigmoidf_(sm[OFF_COEF + 9 * 8 + j] * cm + pre[0] + fgx);
        const float inn = tanhf(pre[2] + inx);
        const float cbase = fgv * cm, cinn = igv * inn;
        const float cmh = cbase + cinn * tm1;
        const float cmn = cbase + cinn * tm2;
        const float ogv = sigmoidf_(sm[OFF_COEF + 11 * 8 + j] * cmh + pre[3] + ogx);
        const float hn  = ogv * tanhf(cmh);
        const float hn2 = swzx8(hn);                 // partner (j^1) value
        if (kh < 4) {
          sm[OFF_CM + ib] = cmn;
          if (!(j & 1)) {                            // paired 8B store: (j, j+1)
            union { float2 f; unsigned long long u; } cv;
            cv.f.x = hn; cv.f.y = hn2;
            unsigned long long* hdst =
                (unsigned long long*)(p.h_buf + (size_t)(cur ^ 1) * BATCH * HF +
                                      (size_t)(b0 + b) * HF + h0 + j);
            __hip_atomic_store(hdst, cv.u, __ATOMIC_RELAXED, __HIP_MEMORY_SCOPE_AGENT);
          }
          if (tc0 + tt == SEQN - 1) {
            p.out[(size_t)(b0 + b) * HF + h0 + j] = hn;
            p.out[(size_t)BATCH * HF + (size_t)(b0 + b) * HF + h0 + j] = cmn;
          }
        }
      }
      post_wave(p.flags, gi, mi, tstep + 1);
      ++tstep;
      cur ^= 1;
    }
  }
}

extern "C" void kernel_launch(void* const* d_in, const int* in_sizes, int n_in,
                              void* d_out, int out_size, void* d_ws, size_t ws_size,
                              hipStream_t stream) {
  (void)in_sizes; (void)n_in; (void)out_size; (void)ws_size;
  Params p;
  p.x = (const float*)d_in[0];
  p.t = (const float*)d_in[1];
  p.w_h[0] = (const float*)d_in[3];   // fg_w_h
  p.w_h[1] = (const float*)d_in[7];   // ig_w_h
  p.w_h[2] = (const float*)d_in[10];  // in_w_h
  p.w_h[3] = (const float*)d_in[14];  // og_w_h
  p.w_x[0] = (const float*)d_in[4];   // fg_w_x
  p.w_x[1] = (const float*)d_in[8];   // ig_w_x
  p.w_x[2] = (const float*)d_in[11];  // in_w_x
  p.w_x[3] = (const float*)d_in[15];  // og_w_x
  p.w_x[4] = (const float*)d_in[18];  // tg1_w_x
  p.w_x[5] = (const float*)d_in[21];  // tg2_w_x
  p.coef[0]  = (const float*)d_in[5];   // fg_b
  p.coef[1]  = (const float*)d_in[9];   // ig_b
  p.coef[2]  = (const float*)d_in[12];  // in_b
  p.coef[3]  = (const float*)d_in[16];  // og_b
  p.coef[4]  = (const float*)d_in[17];  // og_w_t
  p.coef[5]  = (const float*)d_in[19];  // tg1_w_t
  p.coef[6]  = (const float*)d_in[20];  // tg1_b
  p.coef[7]  = (const float*)d_in[22];  // tg2_w_t
  p.coef[8]  = (const float*)d_in[23];  // tg2_b
  p.coef[9]  = (const float*)d_in[2];   // fg_w_c
  p.coef[10] = (const float*)d_in[6];   // ig_w_c
  p.coef[11] = (const float*)d_in[13];  // og_w_cn
  p.flags = (unsigned*)d_ws;                        // [8][32][16] u32 = 16 KiB
  p.h_buf = (float*)((char*)d_ws + 32768);          // [2][B][H] f32 = 256 KiB
  p.out = (float*)d_out;

  hipMemsetAsync(d_ws, 0, 16384, stream);  // wave flags = 0 each call
  hipFuncSetAttribute((const void*)timelstm_kernel,
                      hipFuncAttributeMaxDynamicSharedMemorySize, LDS_BYTES);
  timelstm_kernel<<<dim3(NBLK), dim3(NTHR), LDS_BYTES, stream>>>(p);
}

// Round 8
// 2613.194 us; speedup vs baseline: 2.1266x; 1.1548x over previous
//
#include <hip/hip_runtime.h>
#include <math.h>

#define BATCH 128
#define SEQN  512
#define XF    128
#define HF    256
#define BC    16    // batch tile per block (per group)
#define HC    8     // h tile per block
#define TCH   8     // time-chunk for phase A
#define NBLK  256
#define NTHR  256
#define NGRP  8     // batch groups
#define GSZ   32    // blocks per group (h tiles)

// ---- LDS layout (word offsets), total 29028 words = 116112 B ----
#define OFF_WX   0        // W_x  [k=128][j=8][g=6]           (6144, persistent)
#define OFF_G    6144     // gates [t=8][g=6][b*8+j]          (6144)
#define OFF_X    12288    // union: A: x [k=128][bt swz]      (16384)
                          //        B: per-wave h [4][1024]   (4096)
#define OFF_CM   28672    // cm [b*8+j]                        (128)
#define OFF_TV   28800    // t-values [b*8+t]                  (128)
#define OFF_COEF 28928    // 12 coef vectors x 8               (96)
#define OFF_GO   29024    // LDS "go" counter for waves 1-3
#define LDS_WORDS 29028
#define LDS_BYTES (LDS_WORDS * 4)

struct Params {
  const float* x;
  const float* t;
  const float* w_h[4];   // fg, ig, in, og   [H][H]
  const float* w_x[6];   // fg, ig, in, og, tg1, tg2  [H][X]
  const float* coef[12]; // fg_b, ig_b, in_b, og_b, og_w_t, tg1_w_t, tg1_b, tg2_w_t, tg2_b, fg_w_c, ig_w_c, og_w_cn
  float* h_buf;          // ws: [2][B][H]  (batch-major: coalesced row reads)
  unsigned* flags;       // ws: [NGRP][GSZ][16]  (64B line per block; dword 0 used)
  float* out;
};

__device__ __forceinline__ float sigmoidf_(float v) { return 1.0f / (1.0f + __expf(-v)); }

// in-wave lane exchange (BitMode ds_swizzle: xor<<10 | 0x1F)
__device__ __forceinline__ float swzx1(float v) { return __int_as_float(__builtin_amdgcn_ds_swizzle(__float_as_int(v), 0x041F)); }
__device__ __forceinline__ float swzx2(float v) { return __int_as_float(__builtin_amdgcn_ds_swizzle(__float_as_int(v), 0x081F)); }
__device__ __forceinline__ float swzx4(float v) { return __int_as_float(__builtin_amdgcn_ds_swizzle(__float_as_int(v), 0x101F)); }
__device__ __forceinline__ float swzx8(float v) { return __int_as_float(__builtin_amdgcn_ds_swizzle(__float_as_int(v), 0x201F)); }

// ---- fence-free sync (r1-proven): block-level flag, single poller ---------
// Release: __syncthreads() -> each wave's codegen drains vmcnt(0) before
// s_barrier, so ALL the block's agent h-stores are at the coherence point
// before tid0's relaxed agent flag store issues. Acquire: wave 0 polls the
// 32 block flags of the group, then bumps the LDS go counter; waves 1-3
// spin on LDS. flag >= s  =>  that block finished step s-1 entirely.
__device__ __forceinline__ void post_arrive(unsigned* flags, int gi, int mi, unsigned val) {
  __syncthreads();
  if (threadIdx.x == 0) {
    __hip_atomic_store(&flags[(gi * GSZ + mi) * 16], val,
                       __ATOMIC_RELAXED, __HIP_MEMORY_SCOPE_AGENT);
  }
}

__device__ __forceinline__ void wave_wait(float* sm, const unsigned* flags,
                                          int gi, unsigned target) {
  unsigned* go = (unsigned*)&sm[OFF_GO];
  const int tid = threadIdx.x;
  if (tid < 64) {                      // wave 0: poll the 32 block flags
    const bool need = tid < GSZ;
    const unsigned* f = &flags[(gi * GSZ + (tid & (GSZ - 1))) * 16];
    while (true) {
      unsigned v = need ? __hip_atomic_load(f, __ATOMIC_RELAXED, __HIP_MEMORY_SCOPE_AGENT)
                        : target;
      if (__all((int)(v >= target))) break;
    }
    if (tid == 0)
      __hip_atomic_store(go, target, __ATOMIC_RELAXED, __HIP_MEMORY_SCOPE_WORKGROUP);
  } else {                             // waves 1-3: LDS spin, no fabric traffic
    while (__hip_atomic_load(go, __ATOMIC_RELAXED, __HIP_MEMORY_SCOPE_WORKGROUP) < target) {}
  }
  asm volatile("" ::: "memory");       // keep agent h-loads below the spin
}

__global__ __launch_bounds__(NTHR, 1) void timelstm_kernel(Params p) {
  extern __shared__ float sm[];
  const int tid = threadIdx.x;
  const int bid = blockIdx.x;
  const int gi = bid & 7;          // batch group (XCD-resident under round-robin)
  const int mi = bid >> 3;         // member = h tile
  const int b0 = gi * BC;
  const int h0 = mi * HC;

  const int lane = tid & 63;
  const int bq = tid >> 6;         // wave id = batch quad
  const int kh = lane & 7;         // split-K slice (in-wave reducible)
  const int j  = lane >> 3;        // h feature within tile

  // ---- one-time: W_h -> REGISTERS (per-thread slice, reused all 512 steps)
  float wrs[4][32];
#pragma unroll
  for (int g = 0; g < 4; ++g)
#pragma unroll
    for (int q = 0; q < 8; ++q) {
      const float4 v = *(const float4*)&p.w_h[g][(size_t)(h0 + j) * HF + kh * 32 + q * 4];
      wrs[g][q * 4 + 0] = v.x; wrs[g][q * 4 + 1] = v.y;
      wrs[g][q * 4 + 2] = v.z; wrs[g][q * 4 + 3] = v.w;
    }
  // ---- one-time: W_x slab -> LDS ----
  for (int i = tid; i < 6 * 8 * 128; i += NTHR) {     // W_x: [k][j][g]
    int g = i >> 10, jj = (i >> 7) & 7, k = i & 127;
    sm[OFF_WX + k * 48 + jj * 6 + g] = p.w_x[g][(h0 + jj) * XF + k];
  }
  if (tid < 96) sm[OFF_COEF + tid] = p.coef[tid >> 3][h0 + (tid & 7)];
  if (tid < 128) sm[OFF_CM + tid] = 0.0f;             // cm[b*8+j] = 0
  if (tid == 0) *(unsigned*)&sm[OFF_GO] = 0u;
  // zero h_buf[0] rows b0..b0+15: member 0 of each group (contiguous, agent scope)
  if (mi == 0) {
    unsigned long long* hbu = (unsigned long long*)p.h_buf + (size_t)b0 * (HF / 2);
    for (int i = tid; i < BC * HF / 2; i += NTHR) {
      __hip_atomic_store(&hbu[i], 0ull, __ATOMIC_RELAXED, __HIP_MEMORY_SCOPE_AGENT);
    }
  }
  post_arrive(p.flags, gi, mi, 1u);   // barrier drains the zero-stores first
  unsigned tstep = 1;
  int cur = 0;

  for (int tc0 = 0; tc0 < SEQN; tc0 += TCH) {
    __syncthreads();   // all waves of this block past last chunk's LDS reads
    // ================= phase A: input projections for 8 steps ==========
    // x -> LDS [k=128][bt=128], bt swizzled by ((k>>2)&7)<<2
    {
#pragma unroll
      for (int half = 0; half < 2; ++half) {
        float4 xr[8];
#pragma unroll
        for (int it = 0; it < 8; ++it) {
          const int ri = (half * 8 + it) * 8 + (tid >> 5);   // row = b*8+t
          xr[it] = *(const float4*)&p.x[((size_t)(b0 + (ri >> 3)) * SEQN + (tc0 + (ri & 7))) * XF + (tid & 31) * 4];
        }
#pragma unroll
        for (int it = 0; it < 8; ++it) {
          const int ri = (half * 8 + it) * 8 + (tid >> 5);
          const int k0 = (tid & 31) * 4;
          const float xb[4] = {xr[it].x, xr[it].y, xr[it].z, xr[it].w};
#pragma unroll
          for (int u = 0; u < 4; ++u) {
            const int k = k0 + u;
            sm[OFF_X + k * 128 + (ri ^ (((k >> 2) & 7) << 2))] = xb[u];
          }
        }
      }
      if (tid < 128)   // TV[b*8+t]
        sm[OFF_TV + tid] = p.t[(size_t)(b0 + (tid >> 3)) * SEQN + tc0 + (tid & 7)];
    }
    __syncthreads();
    {
      // thread (c = col-tile of 4 bt, r = j): 6 gates x 4 cols, k = 0..127
      const int c = tid >> 3, r = tid & 7;
      const int c4 = c << 2;
      float a0[4], a1[4], a2[4], a3[4], a4[4], a5[4];
#pragma unroll
      for (int u = 0; u < 4; ++u) { a0[u]=0.f; a1[u]=0.f; a2[u]=0.f; a3[u]=0.f; a4[u]=0.f; a5[u]=0.f; }
      const float* wxp = &sm[OFF_WX + r * 6];
#pragma unroll 4
      for (int k = 0; k < XF; ++k) {
        const float4 xv = *(const float4*)&sm[OFF_X + k * 128 + (c4 ^ (((k >> 2) & 7) << 2))];
        const float2 wA = *(const float2*)&wxp[k * 48 + 0];
        const float2 wB = *(const float2*)&wxp[k * 48 + 2];
        const float2 wC = *(const float2*)&wxp[k * 48 + 4];
        const float xs[4] = {xv.x, xv.y, xv.z, xv.w};
#pragma unroll
        for (int u = 0; u < 4; ++u) {
          a0[u] += wA.x * xs[u]; a1[u] += wA.y * xs[u];
          a2[u] += wB.x * xs[u]; a3[u] += wB.y * xs[u];
          a4[u] += wC.x * xs[u]; a5[u] += wC.y * xs[u];
        }
      }
      const float cfg  = sm[OFF_COEF + 0 * 8 + r], cig  = sm[OFF_COEF + 1 * 8 + r];
      const float cin  = sm[OFF_COEF + 2 * 8 + r];
      const float cogb = sm[OFF_COEF + 3 * 8 + r], cogwt = sm[OFF_COEF + 4 * 8 + r];
      const float ct1w = sm[OFF_COEF + 5 * 8 + r], ct1b = sm[OFF_COEF + 6 * 8 + r];
      const float ct2w = sm[OFF_COEF + 7 * 8 + r], ct2b = sm[OFF_COEF + 8 * 8 + r];
#pragma unroll
      for (int u = 0; u < 4; ++u) {
        const int bt = c4 + u, b = bt >> 3, t = bt & 7;
        const float tv = sm[OFF_TV + bt];
        float* gp = &sm[OFF_G + t * 768 + b * 8 + r];   // [t][g][b*8+j]
        gp[0]   = a0[u] + cfg;
        gp[128] = a1[u] + cig;
        gp[256] = a2[u] + cin;
        gp[384] = a3[u] + cogwt * tv + cogb;
        gp[512] = sigmoidf_(a4[u] + tanhf(ct1w * tv) + ct1b);
        gp[640] = sigmoidf_(a5[u] + tanhf(ct2w * tv) + ct2b);
      }
    }
    __syncthreads();   // phase A done: OFF_X becomes per-wave h space below

    // ================= phase B: 8 recurrent steps, ONE barrier each =======
    // (stage region, cm slice, and gate slice are all wave-private in B)
    for (int tt = 0; tt < TCH; ++tt) {
      wave_wait(sm, p.flags, gi, tstep);
      // wave-private h stage, COALESCED: h_buf is [B][H]; wave bq reads its 4
      // rows (b0+bq*4..+3), each 1KB contiguous (lane l covers cols 4l..4l+3),
      // then transposes into the swizzled wave-private region:
      //   addr(k,bi) = (k*4 ^ ((k>>5)&7)<<2) + bi  -- matmul reads conflict-free.
      // No barrier: region is wave-private; in-order DS pipe handles WAR.
      {
        const unsigned long long* hsrc = (const unsigned long long*)
            (p.h_buf + (size_t)cur * BATCH * HF + (size_t)(b0 + (bq << 2)) * HF);
        unsigned long long v[4][2];
#pragma unroll
        for (int u = 0; u < 4; ++u) {
          const unsigned long long* src = hsrc + (size_t)u * (HF / 2) + lane * 2;
          v[u][0] = __hip_atomic_load(src,     __ATOMIC_RELAXED, __HIP_MEMORY_SCOPE_AGENT);
          v[u][1] = __hip_atomic_load(src + 1, __ATOMIC_RELAXED, __HIP_MEMORY_SCOPE_AGENT);
        }
        float f[4][4];   // [row u][elem e]: h[b=bq*4+u][k=4*lane+e]
#pragma unroll
        for (int u = 0; u < 4; ++u) {
          union { unsigned long long u64; float2 f2; } c0, c1;
          c0.u64 = v[u][0]; c1.u64 = v[u][1];
          f[u][0] = c0.f2.x; f[u][1] = c0.f2.y; f[u][2] = c1.f2.x; f[u][3] = c1.f2.y;
        }
        const int swz = ((lane >> 3) & 7) << 2;
        const int wbase = OFF_X + (bq << 10);
#pragma unroll
        for (int e = 0; e < 4; ++e) {
          const int a = wbase + (((lane << 4) + (e << 2)) ^ swz);
          float2 lo = {f[0][e], f[1][e]};
          float2 hi = {f[2][e], f[3][e]};
          *(float2*)&sm[a]     = lo;   // bi = 0,1
          *(float2*)&sm[a + 2] = hi;   // bi = 2,3
        }
      }

      // matmul: thread (bq, j, kh): acc[bi][g] over k = kh*32..+31, W in regs
      float acc[4][4];
#pragma unroll
      for (int bi = 0; bi < 4; ++bi)
#pragma unroll
        for (int g = 0; g < 4; ++g) acc[bi][g] = 0.f;

      const int hbase = OFF_X + (bq << 10) + (kh << 7);   // + kh*128
      const int khx = kh << 2;
#pragma unroll
      for (int kk = 0; kk < 32; ++kk) {
        const int off = ((((kk & 7) << 2) ^ khx)) + ((kk >> 3) << 5);
        const float4 hv = *(const float4*)&sm[hbase + off];   // h[k][bq*4..+3]
        const float w0 = wrs[0][kk], w1 = wrs[1][kk], w2 = wrs[2][kk], w3 = wrs[3][kk];
        acc[0][0] += hv.x * w0; acc[0][1] += hv.x * w1; acc[0][2] += hv.x * w2; acc[0][3] += hv.x * w3;
        acc[1][0] += hv.y * w0; acc[1][1] += hv.y * w1; acc[1][2] += hv.y * w2; acc[1][3] += hv.y * w3;
        acc[2][0] += hv.z * w0; acc[2][1] += hv.z * w1; acc[2][2] += hv.z * w2; acc[2][3] += hv.z * w3;
        acc[3][0] += hv.w * w0; acc[3][1] += hv.w * w1; acc[3][2] += hv.w * w2; acc[3][3] += hv.w * w3;
      }

      // in-wave reduce-scatter over kh (3 rounds): lane ends with
      // pre[g] = full dot for b = bq*4 + (kh&3)   (kh>=4 duplicates kh-4)
      const int kb0 = kh & 1, kb1 = (kh >> 1) & 1;
      float s1[2][4];
#pragma unroll
      for (int pp = 0; pp < 2; ++pp)
#pragma unroll
        for (int g = 0; g < 4; ++g) {
          const float mine  = kb0 ? acc[2 * pp + 1][g] : acc[2 * pp][g];
          const float yours = kb0 ? acc[2 * pp][g]     : acc[2 * pp + 1][g];
          s1[pp][g] = mine + swzx1(yours);
        }
      float s2[4];
#pragma unroll
      for (int g = 0; g < 4; ++g) {
        const float mine  = kb1 ? s1[1][g] : s1[0][g];
        const float yours = kb1 ? s1[0][g] : s1[1][g];
        s2[g] = mine + swzx2(yours);
      }
      float pre[4];
#pragma unroll
      for (int g = 0; g < 4; ++g) pre[g] = s2[g] + swzx4(s2[g]);

      // gates (all 64 lanes; kh>=4 redundant with kh-4, only kh<4 stores)
      {
        const int bi = kh & 3;
        const int b  = (bq << 2) + bi;
        const int ib = b * 8 + j;
        const float cm = sm[OFF_CM + ib];
        const float* gt = &sm[OFF_G + tt * 768 + ib];
        const float fgx = gt[0],   igx = gt[128], inx = gt[256];
        const float ogx = gt[384], tm1 = gt[512], tm2 = gt[640];
        const float igv = sigmoidf_(sm[OFF_COEF + 10 * 8 + j] * cm + pre[1] + igx);
        const float fgv = sigmoidf_(sm[OFF_COEF + 9 * 8 + j] * cm + pre[0] + fgx);
        const float inn = tanhf(pre[2] + inx);
        const float cbase = fgv * cm, cinn = igv * inn;
        const float cmh = cbase + cinn * tm1;
        const float cmn = cbase + cinn * tm2;
        const float ogv = sigmoidf_(sm[OFF_COEF + 11 * 8 + j] * cmh + pre[3] + ogx);
        const float hn  = ogv * tanhf(cmh);
        const float hn2 = swzx8(hn);                 // partner (j^1) value
        if (kh < 4) {
          sm[OFF_CM + ib] = cmn;
          if (!(j & 1)) {                            // paired 8B store: (j, j+1)
            union { float2 f; unsigned long long u; } cv;
            cv.f.x = hn; cv.f.y = hn2;
            unsigned long long* hdst =
                (unsigned long long*)(p.h_buf + (size_t)(cur ^ 1) * BATCH * HF +
                                      (size_t)(b0 + b) * HF + h0 + j);
            __hip_atomic_store(hdst, cv.u, __ATOMIC_RELAXED, __HIP_MEMORY_SCOPE_AGENT);
          }
          if (tc0 + tt == SEQN - 1) {
            p.out[(size_t)(b0 + b) * HF + h0 + j] = hn;
            p.out[(size_t)BATCH * HF + (size_t)(b0 + b) * HF + h0 + j] = cmn;
          }
        }
      }
      post_arrive(p.flags, gi, mi, tstep + 1);
      ++tstep;
      cur ^= 1;
    }
  }
}

extern "C" void kernel_launch(void* const* d_in, const int* in_sizes, int n_in,
                              void* d_out, int out_size, void* d_ws, size_t ws_size,
                              hipStream_t stream) {
  (void)in_sizes; (void)n_in; (void)out_size; (void)ws_size;
  Params p;
  p.x = (const float*)d_in[0];
  p.t = (const float*)d_in[1];
  p.w_h[0] = (const float*)d_in[3];   // fg_w_h
  p.w_h[1] = (const float*)d_in[7];   // ig_w_h
  p.w_h[2] = (const float*)d_in[10];  // in_w_h
  p.w_h[3] = (const float*)d_in[14];  // og_w_h
  p.w_x[0] = (const float*)d_in[4];   // fg_w_x
  p.w_x[1] = (const float*)d_in[8];   // ig_w_x
  p.w_x[2] = (const float*)d_in[11];  // in_w_x
  p.w_x[3] = (const float*)d_in[15];  // og_w_x
  p.w_x[4] = (const float*)d_in[18];  // tg1_w_x
  p.w_x[5] = (const float*)d_in[21];  // tg2_w_x
  p.coef[0]  = (const float*)d_in[5];   // fg_b
  p.coef[1]  = (const float*)d_in[9];   // ig_b
  p.coef[2]  = (const float*)d_in[12];  // in_b
  p.coef[3]  = (const float*)d_in[16];  // og_b
  p.coef[4]  = (const float*)d_in[17];  // og_w_t
  p.coef[5]  = (const float*)d_in[19];  // tg1_w_t
  p.coef[6]  = (const float*)d_in[20];  // tg1_b
  p.coef[7]  = (const float*)d_in[22];  // tg2_w_t
  p.coef[8]  = (const float*)d_in[23];  // tg2_b
  p.coef[9]  = (const float*)d_in[2];   // fg_w_c
  p.coef[10] = (const float*)d_in[6];   // ig_w_c
  p.coef[11] = (const float*)d_in[13];  // og_w_cn
  p.flags = (unsigned*)d_ws;                        // [8][32][16] u32 = 16 KiB
  p.h_buf = (float*)((char*)d_ws + 32768);          // [2][B][H] f32 = 256 KiB
  p.out = (float*)d_out;

  (void)hipMemsetAsync(d_ws, 0, 16384, stream);  // block flags = 0 each call
  (void)hipFuncSetAttribute((const void*)timelstm_kernel,
                            hipFuncAttributeMaxDynamicSharedMemorySize, LDS_BYTES);
  timelstm_kernel<<<dim3(NBLK), dim3(NTHR), LDS_BYTES, stream>>>(p);
}